// Round 8
// baseline (421.812 us; speedup 1.0000x reference)
//
#include <hip/hip_runtime.h>

// TenHotEncodeLayer: out[n, x[n,j]] = 1.0, rest zeros.
// B=8192 rows, NUM_TOKENS=32000 cols (f32), K=10 indices/row.
//
// R8: single-pass FUSED grid-stride sweep. Keeps R7's winning store pattern
// (256 blocks x 256 thr, grid-stride 65536 float4 = 1MB window sweeping the
// 1GB buffer linearly -> sequential stream per HBM channel), but computes the
// hot bits inline so the scatter pass, its RFO line-fills, and the second
// launch all disappear.
//   chunk c -> row r = c/8000, chunk-in-row ci = c - 8000r.
//   A wave's 64 lanes share a row (8000 chunks/row) except at boundaries;
//   the row's 10 indices are prefetched 1 iteration deep (L1/L2 hits) to
//   cover load latency at 1 wave/SIMD occupancy.

#define NUM_TOKENS 32000
#define KHOT 10
#define F4_PER_ROW (NUM_TOKENS / 4)   // 8000
#define BLOCK 256
#define FILL_GRID 256
#define STRIDE (FILL_GRID * BLOCK)    // 65536 float4 = 1 MB
#define TOTAL_F4 65536000             // 8192 * 8000
#define ITERS (TOTAL_F4 / STRIDE)     // exactly 1000

typedef float f32x4 __attribute__((ext_vector_type(4)));

__global__ __launch_bounds__(BLOCK) void TenHotEncodeLayer_53566832115799_kernel(
    const int* __restrict__ x, f32x4* __restrict__ out) {
    unsigned c = blockIdx.x * BLOCK + threadIdx.x;   // current float4-chunk id

    // Prefetch indices for the row of chunk c (iteration 0).
    int raw[KHOT];
    {
        const unsigned r0 = c / (unsigned)F4_PER_ROW;
        #pragma unroll
        for (int j = 0; j < KHOT; ++j) raw[j] = x[r0 * KHOT + j];
    }

    #pragma unroll 1
    for (int k = 0; k < ITERS; ++k) {
        const unsigned r  = c / (unsigned)F4_PER_ROW;
        const int      ci = (int)(c - r * (unsigned)F4_PER_ROW);

        // Issue NEXT iteration's index loads now (latency hidden under the
        // mask math + store below). Clamp row for the final overrun.
        const unsigned cn = c + STRIDE;
        unsigned rn = cn / (unsigned)F4_PER_ROW;
        if (rn > 8191u) rn = 8191u;
        int nxt[KHOT];
        #pragma unroll
        for (int j = 0; j < KHOT; ++j) nxt[j] = x[rn * KHOT + j];

        // 4-bit hot mask for this chunk. Dup indices OR the same bit (set
        // semantics); out-of-range indices map to cj=-1 (mode="drop").
        unsigned m = 0u;
        #pragma unroll
        for (int j = 0; j < KHOT; ++j) {
            const int idx = raw[j];
            const bool ok = (idx >= 0) && (idx < NUM_TOKENS);
            const int  cj = ok ? (idx >> 2) : -1;
            m |= (cj == ci) ? (1u << (idx & 3)) : 0u;
        }
        f32x4 v;
        v.x = (m & 1u) ? 1.0f : 0.0f;
        v.y = (m & 2u) ? 1.0f : 0.0f;
        v.z = (m & 4u) ? 1.0f : 0.0f;
        v.w = (m & 8u) ? 1.0f : 0.0f;
        out[c] = v;   // plain coalesced 16B store, grid sweeps 1MB/step

        #pragma unroll
        for (int j = 0; j < KHOT; ++j) raw[j] = nxt[j];
        c = cn;
    }
}

extern "C" void kernel_launch(void* const* d_in, const int* in_sizes, int n_in,
                              void* d_out, int out_size, void* d_ws, size_t ws_size,
                              hipStream_t stream) {
    const int* x = (const int*)d_in[0];
    f32x4* out = (f32x4*)d_out;
    TenHotEncodeLayer_53566832115799_kernel<<<FILL_GRID, BLOCK, 0, stream>>>(x, out);
}

// Round 9
// 260.992 us; speedup vs baseline: 1.6162x; 1.6162x over previous
//
#include <hip/hip_runtime.h>

// TenHotEncodeLayer: out[n, x[n,j]] = 1.0, rest zeros.
// B=8192 rows, NUM_TOKENS=32000 cols (f32), K=10 indices/row.
//
// R9: single kernel = R7's grid-stride zero sweep (proven store pattern,
// LOAD-FREE inner loop — R8 showed per-iteration loads kill the 1-wave/SIMD
// streaming regime) + per-block post-sweep ones from a precomputed LDS list.
//   build: every block scans x (int4 loads, ~330KB L2-ish) and keeps the
//          output elements whose chunk g=row*8000+idx/4 lies in its own
//          window slice ((g mod 65536)/256 == blockIdx.x).
//   sweep: pure zero fill, 1 store/iter, grid sweeps one contiguous 1MB
//          window per step (HBM channels see sequential streams).
//   ones:  after __syncthreads (vmcnt drained), write 1.0f to listed
//          elements — the block's OWN lines, still L2-dirty -> no RFO,
//          no second launch, no inter-kernel drain.
// Worst-case per-block list: <=10 per row x ~1032 intersecting rows = 10320.

#define NUM_TOKENS 32000
#define KHOT 10
#define F4_PER_ROW 8000
#define BLOCK 256
#define GRID 256
#define STRIDE (GRID * BLOCK)        // 65536 chunks per window step
#define TOTAL_F4 65536000            // 8192 * 8000
#define ITERS (TOTAL_F4 / STRIDE)    // exactly 1000
#define MAXHOT 12288                 // > worst-case 10320; 48KB LDS (1 blk/CU)

typedef float f32x4 __attribute__((ext_vector_type(4)));
typedef int   i32x4 __attribute__((ext_vector_type(4)));

__global__ __launch_bounds__(BLOCK) void TenHotEncodeLayer_53566832115799_kernel(
    const int* __restrict__ x, float* __restrict__ out, int total) {
    __shared__ unsigned hot[MAXHOT];
    __shared__ int nHot;
    if (threadIdx.x == 0) nHot = 0;
    __syncthreads();

    const unsigned b = blockIdx.x;

    // ---- build: collect this block's hot output-element ids ----
    const i32x4* __restrict__ x4 = (const i32x4*)x;
    const int n4 = total >> 2;                    // 81920/4 = 20480
    for (int v = threadIdx.x; v < n4; v += BLOCK) {
        const i32x4 q = x4[v];
        #pragma unroll
        for (int u = 0; u < 4; ++u) {
            const int e = 4 * v + u;
            const int idx = q[u];
            if (idx < 0 || idx >= NUM_TOKENS) continue;      // mode="drop"
            const unsigned row = (unsigned)e / KHOT;
            const unsigned g = row * F4_PER_ROW + ((unsigned)idx >> 2);
            if (((g & (STRIDE - 1)) >> 8) != b) continue;    // not my slice
            const int s = atomicAdd(&nHot, 1);
            if (s < MAXHOT) hot[s] = row * (unsigned)NUM_TOKENS + (unsigned)idx;
        }
    }
    // no barrier here: the post-sweep __syncthreads covers build visibility

    // ---- sweep: pure grid-stride zero fill (R7's winning pattern) ----
    f32x4* __restrict__ out4 = (f32x4*)out;
    size_t i = (size_t)b * BLOCK + threadIdx.x;
    const f32x4 z = {0.f, 0.f, 0.f, 0.f};
    #pragma unroll 1
    for (int k = 0; k < ITERS; ++k) {
        out4[i] = z;                 // load-free, 1 store/iter
        i += (size_t)STRIDE;
    }

    __syncthreads();                 // drains vmcnt(0) + publishes hot[]/nHot

    // ---- ones: block-local, lines still L2-dirty ----
    const int n = (nHot < MAXHOT) ? nHot : MAXHOT;
    for (int o = threadIdx.x; o < n; o += BLOCK) {
        out[hot[o]] = 1.0f;          // set; duplicate entries benign
    }
}

extern "C" void kernel_launch(void* const* d_in, const int* in_sizes, int n_in,
                              void* d_out, int out_size, void* d_ws, size_t ws_size,
                              hipStream_t stream) {
    const int* x = (const int*)d_in[0];
    float* out = (float*)d_out;
    const int total = in_sizes[0];   // 81920 = B*K
    TenHotEncodeLayer_53566832115799_kernel<<<GRID, BLOCK, 0, stream>>>(x, out, total);
}

// Round 10
// 204.630 us; speedup vs baseline: 2.0613x; 1.2754x over previous
//
#include <hip/hip_runtime.h>

// TenHotEncodeLayer: out[n, x[n,j]] = 1.0, rest zeros.
// B=8192 rows, NUM_TOKENS=32000 cols (f32), K=10 indices/row.
//
// R10: bucket-sort prep + fused load-free sweep.
//  Kernel A: one thread per (row,j). Chunk g = row*8000+idx/4 is stored by
//    sweep (block,thread) = (g>>8 & 255, g & 255) at iteration k = g>>16.
//    Append entry (k<<4)|bitmask as u16 into bucket w = g & 65535 in d_ws
//    (atomic counters, lambda=1.25/bucket, CAP=16).
//  Kernel B: R7's proven grid-stride sweep (256 blk x 256 thr, contiguous
//    1MB window/step, LOAD-FREE loop). Each thread preloads+sorts its own
//    bucket into LDS; per iteration only `if (k==nextK)` (taken ~0.125%),
//    and the 1.0s are merged INTO that iteration's float4 store — zero
//    extra memory ops, no scatter pass, no RFO, no second drain.
//  Lessons encoded: R8 (per-iter loads kill streaming), R9 (per-block
//    O(total) build kills it too), R7 (sweeping window = 6.4+ TB/s).

#define NUM_TOKENS 32000
#define KHOT 10
#define F4_PER_ROW 8000
#define BLOCK 256
#define GRID 256
#define STRIDE (GRID * BLOCK)        // 65536 chunks per window step
#define TOTAL_F4 65536000            // 8192 * 8000
#define ITERS (TOTAL_F4 / STRIDE)    // exactly 1000
#define NBUCKET STRIDE               // one bucket per (block,thread)
#define CAP 16                       // entries/bucket; P(overflow) ~ 1e-8
#define WS_NEEDED (NBUCKET * 4 + NBUCKET * CAP * 2)   // 256KB cnt + 2MB ent

typedef float f32x4 __attribute__((ext_vector_type(4)));

// ---------------- Kernel A: bucket the hot elements ----------------
__global__ __launch_bounds__(BLOCK) void tenhot_bucket(
    const int* __restrict__ x, unsigned* __restrict__ cnt,
    unsigned short* __restrict__ ent, int total) {
    const int t = blockIdx.x * BLOCK + threadIdx.x;
    if (t >= total) return;
    const int idx = x[t];
    if (idx < 0 || idx >= NUM_TOKENS) return;          // mode="drop"
    const unsigned row = (unsigned)t / KHOT;
    const unsigned g = row * F4_PER_ROW + ((unsigned)idx >> 2);
    const unsigned w = g & (NBUCKET - 1);              // (block<<8)|thread
    const unsigned k = g >> 16;                        // iteration 0..999
    const unsigned pos = atomicAdd(&cnt[w], 1u);
    if (pos < CAP)
        ent[w * CAP + pos] = (unsigned short)((k << 4) | (1u << (idx & 3)));
}

// ---------------- Kernel B: sweep with fused ones ----------------
__global__ __launch_bounds__(BLOCK) void tenhot_sweep(
    const unsigned* __restrict__ cnt, const unsigned short* __restrict__ ent,
    f32x4* __restrict__ out4) {
    __shared__ unsigned short lst[BLOCK][CAP];
    const unsigned t = threadIdx.x;
    const unsigned w = blockIdx.x * BLOCK + t;

    // Pre-sweep: load my bucket (avg 1.25 entries) and insertion-sort by k.
    unsigned n = cnt[w];
    if (n > CAP) n = CAP;
    for (unsigned s = 0; s < n; ++s) lst[t][s] = ent[w * CAP + s];
    for (unsigned a = 1; a < n; ++a) {
        const unsigned short e = lst[t][a];
        int p = (int)a - 1;
        while (p >= 0 && (unsigned)(lst[t][p] >> 4) > (unsigned)(e >> 4)) {
            lst[t][p + 1] = lst[t][p];
            --p;
        }
        lst[t][p + 1] = e;
    }
    unsigned cur = 0;
    unsigned nextK = (cur < n) ? (unsigned)(lst[t][cur] >> 4) : 0xFFFFu;

    // Sweep: identical store pattern to R7 (load-free, 1 store/iter).
    size_t i = (size_t)blockIdx.x * BLOCK + t;
    const f32x4 z = {0.f, 0.f, 0.f, 0.f};
    #pragma unroll 1
    for (unsigned k = 0; k < ITERS; ++k) {
        f32x4 v = z;
        if (k == nextK) {                  // rare: ~1.25 times per thread total
            do {                           // while-loop handles same-k entries
                const unsigned m = lst[t][cur] & 0xFu;
                if (m & 1u) v.x = 1.0f;
                if (m & 2u) v.y = 1.0f;
                if (m & 4u) v.z = 1.0f;
                if (m & 8u) v.w = 1.0f;    // dup indices: same bit set twice, benign
                ++cur;
                nextK = (cur < n) ? (unsigned)(lst[t][cur] >> 4) : 0xFFFFu;
            } while (nextK == k);
        }
        out4[i] = v;                       // the one rides the streaming store
        i += (size_t)STRIDE;
    }
}

// ---------------- Fallback (R7): if d_ws is too small ----------------
__global__ __launch_bounds__(BLOCK) void tenhot_fill0(f32x4* __restrict__ out) {
    size_t i = (size_t)blockIdx.x * BLOCK + threadIdx.x;
    const f32x4 z = {0.f, 0.f, 0.f, 0.f};
    #pragma unroll 1
    for (int k = 0; k < ITERS; ++k) {
        out[i] = z;
        i += (size_t)STRIDE;
    }
}

__global__ __launch_bounds__(BLOCK) void tenhot_scatter(
    const int* __restrict__ x, float* __restrict__ out, int total) {
    const int t = blockIdx.x * BLOCK + threadIdx.x;
    if (t < total) {
        const int idx = x[t];
        const int row = t / KHOT;
        if (idx >= 0 && idx < NUM_TOKENS)
            out[(size_t)row * NUM_TOKENS + idx] = 1.0f;
    }
}

extern "C" void kernel_launch(void* const* d_in, const int* in_sizes, int n_in,
                              void* d_out, int out_size, void* d_ws, size_t ws_size,
                              hipStream_t stream) {
    const int* x = (const int*)d_in[0];
    float* out = (float*)d_out;
    const int total = in_sizes[0];   // 81920 = B*K
    if (ws_size >= (size_t)WS_NEEDED) {
        unsigned* cnt = (unsigned*)d_ws;
        unsigned short* ent = (unsigned short*)((char*)d_ws + NBUCKET * 4);
        hipMemsetAsync(d_ws, 0, NBUCKET * 4, stream);   // re-zero counters every call
        tenhot_bucket<<<(total + BLOCK - 1) / BLOCK, BLOCK, 0, stream>>>(x, cnt, ent, total);
        tenhot_sweep<<<GRID, BLOCK, 0, stream>>>(cnt, ent, (f32x4*)out);
    } else {
        tenhot_fill0<<<GRID, BLOCK, 0, stream>>>((f32x4*)out);
        tenhot_scatter<<<(total + BLOCK - 1) / BLOCK, BLOCK, 0, stream>>>(x, out, total);
    }
}

// Round 11
// 188.796 us; speedup vs baseline: 2.2342x; 1.0839x over previous
//
#include <hip/hip_runtime.h>

// TenHotEncodeLayer: out[n, x[n,j]] = 1.0, rest zeros.
// B=8192 rows, NUM_TOKENS=32000 cols (f32), K=10 indices/row.
//
// R11: delegate the bulk zero-fill to hipMemsetAsync — its implementation
// (__amd_rocclr_fillBufferAligned) is the fastest writer measured on this
// chip (6.8-6.9 TB/s, proven every round by the harness's own poison
// dispatches; graph-capture safety of hipMemsetAsync proven by R10's run).
// Then a tiny scatter kernel writes the 81,920 ones (latency-parallel,
// ~21 MB of RFO traffic, int4-vectorized index loads).
// Lessons encoded: R8/R9/R10 — any "smart" fused fill loses to dumb-fill +
// tiny-scatter; don't hand-roll what rocclr already does at peak.

#define NUM_TOKENS 32000
#define KHOT 10
#define BLOCK 256

typedef int i32x4 __attribute__((ext_vector_type(4)));

__global__ __launch_bounds__(BLOCK) void tenhot_scatter(
    const int* __restrict__ x, float* __restrict__ out, int total) {
    // One thread per 4 consecutive (row,j) elements: 16B coalesced index
    // loads, 4 independent scatter stores in flight per thread.
    const int v = blockIdx.x * BLOCK + threadIdx.x;
    const int e0 = 4 * v;
    if (e0 >= total) return;
    const i32x4 q = *reinterpret_cast<const i32x4*>(x + e0);
    #pragma unroll
    for (int u = 0; u < 4; ++u) {
        const int e = e0 + u;
        if (e < total) {
            const int idx = q[u];
            if (idx >= 0 && idx < NUM_TOKENS) {          // mode="drop"
                const unsigned row = (unsigned)e / KHOT;
                out[(size_t)row * NUM_TOKENS + idx] = 1.0f;  // set; dups benign
            }
        }
    }
}

extern "C" void kernel_launch(void* const* d_in, const int* in_sizes, int n_in,
                              void* d_out, int out_size, void* d_ws, size_t ws_size,
                              hipStream_t stream) {
    const int* x = (const int*)d_in[0];
    float* out = (float*)d_out;
    const int total = in_sizes[0];                        // 81920 = B*K
    // Bulk zero at rocclr-fill speed (6.8+ TB/s measured on this chip).
    hipMemsetAsync(d_out, 0, (size_t)out_size * sizeof(float), stream);
    // 81,920 ones, latency-parallel.
    const int nthreads = (total + 3) / 4;                 // 20480
    tenhot_scatter<<<(nthreads + BLOCK - 1) / BLOCK, BLOCK, 0, stream>>>(x, out, total);
}